// Round 5
// baseline (104.084 us; speedup 1.0000x reference)
//
#include <hip/hip_runtime.h>

// 8-row x 4-col tiles, one wave per block (64 threads).
// Tiles per batch: s1 (256²): 32x64=2048, s2 (128²): 16x32=512, s3 (64²): 8x16=128
// => 2688 tiles/batch = 42 waves/batch; x64 batches = 2688 blocks of 64 threads.
#define TPB   2688           // tiles (=threads) per batch
#define B1    2048           // scale-1 tiles per batch
#define B2    2560           // scale-1+2
#define NWAVE (TPB)          // one wave-partial slot per wave... (42*64 = 2688 waves total)
#define NPART 2688           // total wave partials per component
#define WPB   42             // waves (partials) per batch

template<int W>
__device__ __forceinline__ void load_row(const float* __restrict__ h, int r,
                                         int j0, bool fullj, float a[8]) {
    const float* p = h + r * W + (j0 - 1);   // j0-1 = 4*tx -> 16B aligned
    float4 lo = *(const float4*)p;
    a[0] = lo.x; a[1] = lo.y; a[2] = lo.z; a[3] = lo.w;
    float4 hi = make_float4(0.f, 0.f, 0.f, 0.f);
    if (fullj) hi = *(const float4*)(p + 4);   // predicated off on last strip (no OOB)
    a[4] = hi.x; a[5] = hi.y; a[6] = hi.z; a[7] = hi.w;
}

template<int W, int R>
__device__ __forceinline__ void do_tile(const float* __restrict__ h,
                                        int ty, int tx,
                                        int& sy, int& sx, int& cnt) {
    const int i0 = 1 + 8 * ty;                 // 8 rows per tile
    const int j0 = 1 + 4 * tx;                 // 4 cols per tile
    const int ilast = min(i0 + 7, W - 2);      // bottom tile: only 6 valid rows
    const bool fullj = (j0 + 6 <= W - 1);      // last strip: load only 1 float4

    // All 10 window rows up front: up to 20 independent global_load_dwordx4.
    // Row index clamped to ilast+1 (<= W-1): never reads past the channel.
    float a[10][8];
    #pragma unroll
    for (int rr = 0; rr < 10; rr++) {
        const int r = min(i0 - 1 + rr, ilast + 1);
        load_row<W>(h, r, j0, fullj, a[rr]);
    }

    #pragma unroll
    for (int k = 0; k < 8; k++) {
        const int i = i0 + k;
        if (i <= ilast) {
            const float* top = a[k];
            const float* mid = a[k + 1];
            const float* bot = a[k + 2];
            #pragma unroll
            for (int p = 0; p < 4; p++) {
                const float c = mid[p + 1];
                bool pk = (c > top[p]) & (c > top[p + 1]) & (c > top[p + 2])
                        & (c > mid[p]) & (c > mid[p + 2])
                        & (c > bot[p]) & (c > bot[p + 1]) & (c > bot[p + 2]);
                if (pk && (j0 + p <= W - 2)) {
                    sy += R * i; sx += R * (j0 + p); cnt++;
                }
            }
        }
    }
}

__device__ __forceinline__ int wave_reduce_i(int v) {
    #pragma unroll
    for (int o = 32; o > 0; o >>= 1) v += __shfl_down(v, o, 64);
    return v;
}

__global__ __launch_bounds__(64) void peaks_kernel(
    const float* __restrict__ p1, const float* __restrict__ p2,
    const float* __restrict__ p3, int* __restrict__ ws) {
    const int tid = blockIdx.x * 64 + threadIdx.x;   // < 172032
    const int n   = tid / TPB;                       // batch (magic-mul)
    const int q   = tid - n * TPB;                   // tile within batch

    int sy = 0, sx = 0, c = 0;
    if (q < B1) {                                    // wave-uniform (2048 % 64 == 0)
        do_tile<256, 4>(p1 + n * 196608 + 131072, q >> 6, q & 63, sy, sx, c);
    } else if (q < B2) {                             // 2560 % 64 == 0
        const int q2 = q - B1;
        do_tile<128, 8>(p2 + n * 49152 + 32768, q2 >> 5, q2 & 31, sy, sx, c);
    } else {                                         // 2688 % 64 == 0
        const int q3 = q - B2;
        do_tile<64, 16>(p3 + n * 12288 + 8192, q3 >> 4, q3 & 15, sy, sx, c);
    }

    sy = wave_reduce_i(sy);
    sx = wave_reduce_i(sx);
    c  = wave_reduce_i(c);

    // One partial slot per wave (= per block). Poison-proof: plain stores.
    if (threadIdx.x == 0) {
        const int w = blockIdx.x;                    // wave id == block id
        ws[w]             = sy;
        ws[NPART + w]     = sx;
        ws[2 * NPART + w] = c;
    }
}

__global__ __launch_bounds__(64) void finalize_kernel(
    const int* __restrict__ ws, const float* __restrict__ target,
    float* __restrict__ out) {
    const int n = threadIdx.x;  // 0..63 = batch index, single wave

    int isy = 0, isx = 0, cnt = 0;
    #pragma unroll
    for (int b = 0; b < WPB; b++) {
        const int slot = n * WPB + b;
        isy += ws[slot];
        isx += ws[NPART + slot];
        cnt += ws[2 * NPART + slot];
    }
    const float csy = (float)isy;
    const float csx = (float)isx;

    float ty = 0.f, tx = 0.f;
    const float* t = target + n * 160;
    #pragma unroll 8
    for (int k = 0; k < 32; k++) {
        ty += (t[k * 5 + 2] + t[k * 5 + 0]) * 0.5f;
        tx += (t[k * 5 + 3] + t[k * 5 + 1]) * 0.5f;
    }

    float dy = fabsf(csy - ty);
    float dx = fabsf(csx - tx);
    double offx = (dy < 1.f) ? 0.5 * (double)dy * dy : (double)dy - 0.5;
    double offy = (dx < 1.f) ? 0.5 * (double)dx * dx : (double)dx - 0.5;

    double cy_t = csy, cx_t = csx, ty_t = ty, tx_t = tx, pcnt = cnt;

    #pragma unroll
    for (int o = 32; o > 0; o >>= 1) {
        offx += __shfl_down(offx, o, 64);
        offy += __shfl_down(offy, o, 64);
        cy_t += __shfl_down(cy_t, o, 64);
        cx_t += __shfl_down(cx_t, o, 64);
        ty_t += __shfl_down(ty_t, o, 64);
        tx_t += __shfl_down(tx_t, o, 64);
        pcnt += __shfl_down(pcnt, o, 64);
    }

    if (n == 0) {
        double sgnx = offx / fabs(offx);
        double sgny = offy / fabs(offy);
        double loss = (sgnx * (cy_t - ty_t) + sgny * (cx_t - tx_t)) / pcnt;
        out[0] = (float)loss;
    }
}

extern "C" void kernel_launch(void* const* d_in, const int* in_sizes, int n_in,
                              void* d_out, int out_size, void* d_ws, size_t ws_size,
                              hipStream_t stream) {
    const float* p1     = (const float*)d_in[0];
    const float* p2     = (const float*)d_in[1];
    const float* p3     = (const float*)d_in[2];
    const float* target = (const float*)d_in[3];
    float* out = (float*)d_out;
    int*   ws  = (int*)d_ws;

    peaks_kernel<<<2688, 64, 0, stream>>>(p1, p2, p3, ws);
    finalize_kernel<<<1, 64, 0, stream>>>(ws, target, out);
}